// Round 7
// baseline (232.786 us; speedup 1.0000x reference)
//
#include <hip/hip_runtime.h>
#include <math.h>

// InfiniAttention fused forward, MI355X round 7.
// B=4, N=2048, DIM=64, H=8, DH=64.
// Round-7: k_flash re-gridded to 64-row Q blocks (grid 1024 -> 4 blocks/CU;
// round-6 was grid-capped at 2 blocks/CU, Occupancy 18%). One 16-row strip
// per wave. exp scale folded into exp2f. All other kernels byte-identical to
// the round-6 PASS (k_memacc split-bf16 MFMA, k_gv, tight kh chain).
//
// Workspace (floats, 16908288 total = 67,633,152 B):
//   kh   @ 0         f32  4194304
//   qb   @ 4194304   bf16 [bh][n][d]
//   kb   @ 6291456   bf16 [bh][n][d]
//   vb   @ 8388608   bf16 [bh][n][d]
//   vbT  @ 10485760  bf16 [bh][e][n]
//   Gv   @ 12582912  f32  131072  [bh][d][e]
//   pm   @ 12713984  f32  2097152 (16 chunks)  <- o bf16 aliases pm
//   pg   @ 14811136  f32  2097152

#define B_   4
#define N_   2048
#define H_   8
#define BH_  32
#define KP   72      // bf16 LDS pitch (144 B)

typedef __bf16 bf16x8 __attribute__((ext_vector_type(8)));
typedef __bf16 bf16x4 __attribute__((ext_vector_type(4)));
typedef float  f32x4  __attribute__((ext_vector_type(4)));

__device__ __forceinline__ float eluf(float x) {
    return x > 0.0f ? x : expm1f(x);   // expm1 critical near 0
}

// ---------------- K2: head projections (unchanged from round-5/6 PASS) --------
__global__ __launch_bounds__(256) void k_proj(
    const float* __restrict__ q, const float* __restrict__ k, const float* __restrict__ v,
    const float* __restrict__ Wq, const float* __restrict__ Wk, const float* __restrict__ Wv,
    __bf16* __restrict__ qb, float* __restrict__ kh, __bf16* __restrict__ kb,
    __bf16* __restrict__ vb, __bf16* __restrict__ vbT)
{
    const int which = blockIdx.z;
    const float* __restrict__ src = (which == 0) ? q : (which == 1) ? k : v;
    const float* __restrict__ W   = (which == 0) ? Wq : (which == 1) ? Wk : Wv;
    const int h    = blockIdx.y;
    const int row0 = blockIdx.x * 64;   // over B*N = 8192

    __shared__ __align__(16) float AsT[64][68];   // [dim][row]
    __shared__ __align__(16) float WsT[64][68];   // [dim][col]; reused for v^T
    const int tid = threadIdx.x;
    for (int s = 0; s < 16; ++s) {
        int flat = s * 256 + tid;
        int r = flat >> 6, d = flat & 63;
        AsT[d][r] = src[(size_t)(row0 + r) * 64 + d];
        WsT[d][r] = W[(size_t)(h * 64 + r) * 64 + d];
    }
    __syncthreads();

    const int ty = tid >> 4, tx = tid & 15;
    float acc[4][4];
    #pragma unroll
    for (int i = 0; i < 4; ++i)
        #pragma unroll
        for (int j = 0; j < 4; ++j) acc[i][j] = 0.0f;
    for (int kd = 0; kd < 64; ++kd) {
        float4 a4 = *(const float4*)&AsT[kd][ty * 4];
        float4 w4 = *(const float4*)&WsT[kd][tx * 4];
        float a[4] = {a4.x, a4.y, a4.z, a4.w};
        float w[4] = {w4.x, w4.y, w4.z, w4.w};
        #pragma unroll
        for (int i = 0; i < 4; ++i)
            #pragma unroll
            for (int j = 0; j < 4; ++j) acc[i][j] = fmaf(a[i], w[j], acc[i][j]);
    }

    const int b = row0 >> 11, nb = row0 & 2047;
    if (which == 0) {
        #pragma unroll
        for (int i = 0; i < 4; ++i) {
            size_t idx = ((((size_t)b * H_ + h) * N_ + nb + ty * 4 + i) << 6) + tx * 4;
            bf16x4 o4 = {(__bf16)acc[i][0], (__bf16)acc[i][1],
                         (__bf16)acc[i][2], (__bf16)acc[i][3]};
            *(bf16x4*)&qb[idx] = o4;
        }
    } else if (which == 1) {
        #pragma unroll
        for (int i = 0; i < 4; ++i) {
            size_t idx = ((((size_t)b * H_ + h) * N_ + nb + ty * 4 + i) << 6) + tx * 4;
            *(float4*)&kh[idx] = make_float4(acc[i][0], acc[i][1], acc[i][2], acc[i][3]);
            bf16x4 o4 = {(__bf16)acc[i][0], (__bf16)acc[i][1],
                         (__bf16)acc[i][2], (__bf16)acc[i][3]};
            *(bf16x4*)&kb[idx] = o4;
        }
    } else {
        #pragma unroll
        for (int i = 0; i < 4; ++i) {
            size_t idx = ((((size_t)b * H_ + h) * N_ + nb + ty * 4 + i) << 6) + tx * 4;
            bf16x4 o4 = {(__bf16)acc[i][0], (__bf16)acc[i][1],
                         (__bf16)acc[i][2], (__bf16)acc[i][3]};
            *(bf16x4*)&vb[idx] = o4;
        }
        __syncthreads();
        #pragma unroll
        for (int i = 0; i < 4; ++i)
            #pragma unroll
            for (int j = 0; j < 4; ++j) WsT[tx * 4 + j][ty * 4 + i] = acc[i][j];
        __syncthreads();
        const int e = tid >> 2, nc = (tid & 3) * 16;
        bf16x8 lo, hi;
        #pragma unroll
        for (int jj = 0; jj < 8; ++jj) {
            lo[jj] = (__bf16)WsT[e][nc + jj];
            hi[jj] = (__bf16)WsT[e][nc + 8 + jj];
        }
        size_t base = (((size_t)b * H_ + h) * 64 + e) * (size_t)N_ + nb + nc;
        *(bf16x8*)&vbT[base]     = lo;
        *(bf16x8*)&vbT[base + 8] = hi;
    }
}

// ---- K3: memory-update on split-bf16 MFMA (unchanged from round-6 PASS) ----
__global__ __launch_bounds__(256) void k_memacc(
    const float* __restrict__ kh, const __bf16* __restrict__ vb,
    const float* __restrict__ mem, const float* __restrict__ mem_norm,
    float* __restrict__ pmem, float* __restrict__ out_norm)
{
    const int chunk = blockIdx.x;    // 0..15
    const int bh    = blockIdx.y;
    const int h     = bh & 7;
    const int n0    = chunk * 128;

    __shared__ __align__(16) __bf16 memT_hi[64 * KP], memT_lo[64 * KP]; // [e][d]
    __shared__ __align__(16) __bf16 ekn_hi[64 * KP],  ekn_lo[64 * KP];  // [n][d]
    __shared__ __align__(16) __bf16 ekT_hi[64 * KP],  ekT_lo[64 * KP];  // [d][n]
    __shared__ __align__(16) __bf16 vtT_hi[64 * KP],  vtT_lo[64 * KP];  // [e][n]

    const int tid  = threadIdx.x;
    const int w    = tid >> 6, lane = tid & 63;
    const int quad = lane >> 4, m = lane & 15;

    for (int s = 0; s < 16; ++s) {
        int flat = s * 256 + tid;          // flat = d*64 + e
        int d = flat >> 6, e = flat & 63;
        float mv = mem[(size_t)h * 4096 + flat];
        __bf16 hi = (__bf16)mv;
        memT_hi[e * KP + d] = hi;
        memT_lo[e * KP + d] = (__bf16)(mv - (float)hi);
    }

    f32x4 accM[4];
    #pragma unroll
    for (int t = 0; t < 4; ++t) { f32x4 z = {0.f, 0.f, 0.f, 0.f}; accM[t] = z; }
    __syncthreads();

    for (int sub = 0; sub < 2; ++sub) {
        const int nb = n0 + sub * 64;
        for (int rr = w; rr < 64; rr += 4) {
            const int n = nb + rr;
            float ekv = eluf(kh[((size_t)bh * N_ + n) * 64 + lane]);
            __bf16 hi = (__bf16)ekv;
            __bf16 lo = (__bf16)(ekv - (float)hi);
            ekn_hi[rr * KP + lane] = hi;
            ekn_lo[rr * KP + lane] = lo;
            ekT_hi[lane * KP + rr] = hi;
            ekT_lo[lane * KP + rr] = lo;
            float srt = ekv;
            #pragma unroll
            for (int m2 = 32; m2; m2 >>= 1) srt += __shfl_xor(srt, m2, 64);
            if (lane == 0) out_norm[(size_t)bh * N_ + n] = srt;
        }
        __syncthreads();

        f32x4 km[4];
        #pragma unroll
        for (int t = 0; t < 4; ++t) { f32x4 z = {0.f, 0.f, 0.f, 0.f}; km[t] = z; }
        #pragma unroll
        for (int c2 = 0; c2 < 2; ++c2) {
            bf16x8 Ah = *(const bf16x8*)&ekn_hi[(w * 16 + m) * KP + c2 * 32 + quad * 8];
            bf16x8 Al = *(const bf16x8*)&ekn_lo[(w * 16 + m) * KP + c2 * 32 + quad * 8];
            #pragma unroll
            for (int et = 0; et < 4; ++et) {
                bf16x8 Bh = *(const bf16x8*)&memT_hi[(et * 16 + m) * KP + c2 * 32 + quad * 8];
                bf16x8 Bl = *(const bf16x8*)&memT_lo[(et * 16 + m) * KP + c2 * 32 + quad * 8];
                km[et] = __builtin_amdgcn_mfma_f32_16x16x32_bf16(Al, Bh, km[et], 0, 0, 0);
                km[et] = __builtin_amdgcn_mfma_f32_16x16x32_bf16(Ah, Bl, km[et], 0, 0, 0);
                km[et] = __builtin_amdgcn_mfma_f32_16x16x32_bf16(Ah, Bh, km[et], 0, 0, 0);
            }
        }
        float nrmv[4];
        #pragma unroll
        for (int r = 0; r < 4; ++r)
            nrmv[r] = mem_norm[(size_t)h * N_ + nb + w * 16 + quad * 4 + r];
        #pragma unroll
        for (int et = 0; et < 4; ++et) {
            #pragma unroll
            for (int r = 0; r < 4; ++r) {
                const int nl = w * 16 + quad * 4 + r;
                const int e  = et * 16 + m;
                float vh  = (float)vb[((size_t)bh * N_ + nb + nl) * 64 + e];
                float ekv = (float)ekn_hi[nl * KP + e] + (float)ekn_lo[nl * KP + e];
                float vt  = vh - km[et][r] / (ekv * nrmv[r]);
                __bf16 hi = (__bf16)vt;
                vtT_hi[e * KP + nl] = hi;
                vtT_lo[e * KP + nl] = (__bf16)(vt - (float)hi);
            }
        }
        __syncthreads();

        #pragma unroll
        for (int c2 = 0; c2 < 2; ++c2) {
            bf16x8 Ah = *(const bf16x8*)&ekT_hi[(w * 16 + m) * KP + c2 * 32 + quad * 8];
            bf16x8 Al = *(const bf16x8*)&ekT_lo[(w * 16 + m) * KP + c2 * 32 + quad * 8];
            #pragma unroll
            for (int et = 0; et < 4; ++et) {
                bf16x8 Bh = *(const bf16x8*)&vtT_hi[(et * 16 + m) * KP + c2 * 32 + quad * 8];
                bf16x8 Bl = *(const bf16x8*)&vtT_lo[(et * 16 + m) * KP + c2 * 32 + quad * 8];
                accM[et] = __builtin_amdgcn_mfma_f32_16x16x32_bf16(Al, Bh, accM[et], 0, 0, 0);
                accM[et] = __builtin_amdgcn_mfma_f32_16x16x32_bf16(Ah, Bl, accM[et], 0, 0, 0);
                accM[et] = __builtin_amdgcn_mfma_f32_16x16x32_bf16(Ah, Bh, accM[et], 0, 0, 0);
            }
        }
        __syncthreads();
    }

    const size_t base = ((size_t)chunk * BH_ + bh) * 4096;
    #pragma unroll
    for (int et = 0; et < 4; ++et)
        #pragma unroll
        for (int r = 0; r < 4; ++r)
            pmem[base + (size_t)(w * 16 + quad * 4 + r) * 64 + et * 16 + m] =
                accM[et][r];
}

// ---- K3g: Gv partials = Wg^T @ vh (unchanged from round-6 PASS) ----
__global__ __launch_bounds__(256) void k_gv(
    const float* __restrict__ Wg, const __bf16* __restrict__ vbT,
    float* __restrict__ pGv)
{
    const int chunk = blockIdx.x;    // 0..15
    const int bh    = blockIdx.y;
    const int n0    = chunk * 128;
    __shared__ __align__(16) __bf16 WgT[64 * 136];   // [d][n], pitch 272B
    const int tid  = threadIdx.x;
    const int w    = tid >> 6, lane = tid & 63;
    const int quad = lane >> 4, m = tid & 15;

    for (int s = 0; s < 8; ++s) {
        int f4 = s * 256 + tid;
        int n = f4 >> 4, dg = (f4 & 15) * 4;
        float4 wv = *(const float4*)&Wg[(size_t)(n0 + n) * 64 + dg];
        WgT[(dg + 0) * 136 + n] = (__bf16)wv.x;
        WgT[(dg + 1) * 136 + n] = (__bf16)wv.y;
        WgT[(dg + 2) * 136 + n] = (__bf16)wv.z;
        WgT[(dg + 3) * 136 + n] = (__bf16)wv.w;
    }
    __syncthreads();

    f32x4 acc[4];
    #pragma unroll
    for (int t = 0; t < 4; ++t) { f32x4 z = {0.f, 0.f, 0.f, 0.f}; acc[t] = z; }
    #pragma unroll
    for (int c = 0; c < 4; ++c) {
        bf16x8 Af = *(const bf16x8*)&WgT[(w * 16 + m) * 136 + c * 32 + quad * 8];
        #pragma unroll
        for (int et = 0; et < 4; ++et) {
            bf16x8 Bf = *(const bf16x8*)&vbT[((size_t)bh * 64 + et * 16 + m) * N_ +
                                             n0 + c * 32 + quad * 8];
            acc[et] = __builtin_amdgcn_mfma_f32_16x16x32_bf16(Af, Bf, acc[et], 0, 0, 0);
        }
    }
    const size_t base = ((size_t)chunk * BH_ + bh) * 4096;
    #pragma unroll
    for (int et = 0; et < 4; ++et)
        #pragma unroll
        for (int r = 0; r < 4; ++r)
            pGv[base + (size_t)(w * 16 + quad * 4 + r) * 64 + et * 16 + m] =
                acc[et][r];
}

// ---------------- K3b: reduce partials (unchanged) ----------------
__global__ __launch_bounds__(256) void k_reduce(
    const float* __restrict__ mem, const float* __restrict__ pmem,
    const float* __restrict__ pGv, float* __restrict__ out_mem, float* __restrict__ Gv)
{
    const int idx = blockIdx.x * 256 + threadIdx.x;
    const int bh = idx >> 12, h = bh & 7, de = idx & 4095;
    float sm = mem[(size_t)h * 4096 + de];
    float sg = 0.0f;
    #pragma unroll
    for (int c = 0; c < 16; ++c) {
        sm += pmem[(size_t)c * 131072 + idx];
        sg += pGv[(size_t)c * 131072 + idx];
    }
    out_mem[idx] = sm;
    Gv[idx] = sg;
}

// ---------- K4: flash attention, 64-row blocks (4 blocks/CU) ----------
// grid (32,32); 256 thr = 4 waves; wave owns one 16-row strip.
// S^T = K*Q^T; no-max softmax (exp2 with folded scale); gated epilogue MFMA.
__global__ __launch_bounds__(256, 4) void k_flash(
    const __bf16* __restrict__ qb, const __bf16* __restrict__ kb,
    const __bf16* __restrict__ vbT, const float* __restrict__ mem,
    const float* __restrict__ mem_norm, const float* __restrict__ Gv,
    const float* __restrict__ s_local_p, const float* __restrict__ s_long_p,
    __bf16* __restrict__ o)
{
    const int n0 = blockIdx.x * 64;
    const int bh = blockIdx.y;
    const int h  = bh & 7;
    const __bf16* __restrict__ kbp = kb  + (size_t)bh * N_ * 64;
    const __bf16* __restrict__ vtp = vbT + (size_t)bh * 64 * N_;

    __shared__ __align__(16) __bf16 Kb[64 * KP];   // [kcol][d]; epilogue: MT [e][d]
    __shared__ __align__(16) __bf16 VT[64 * KP];   // [e][n];   epilogue: GT [e][d]
    __shared__ __align__(16) __bf16 Pw[64 * KP];   // [qrow][kcol] per-wave strips
    __shared__ float lsl[64];
    __shared__ float nrm_l[64];

    const int tid  = threadIdx.x;
    const int w    = tid >> 6, lane = tid & 63;
    const int quad = lane >> 4, m = lane & 15;
    const float gl   = 1.0f - 1.0f / (1.0f + __expf(-s_local_p[0]));
    const float sigg = 1.0f / (1.0f + __expf(-s_long_p[0]));
    const float SCL  = 0.18033688f;   // 0.125 * log2(e), folded into exp2

    if (tid < 64) nrm_l[tid] = mem_norm[(size_t)h * N_ + n0 + tid];

    // Q B-fragments (regs for whole kernel): lane holds Q[qrow=m][d=quad*8+j]
    const size_t q0 = ((size_t)bh * N_ + n0 + w * 16 + m) * 64;
    bf16x8 qa0 = *(const bf16x8*)&qb[q0 + quad * 8];
    bf16x8 qa1 = *(const bf16x8*)&qb[q0 + 32 + quad * 8];

    f32x4 O[4];
    #pragma unroll
    for (int t = 0; t < 4; ++t) { f32x4 z = {0.f, 0.f, 0.f, 0.f}; O[t] = z; }
    float lsum = 0.f;
    const int prow = w * 16;

    const int srow = tid >> 2, scg = (tid & 3) * 16;
    bf16x8 pk0 = *(const bf16x8*)&kbp[(size_t)srow * 64 + scg];
    bf16x8 pk1 = *(const bf16x8*)&kbp[(size_t)srow * 64 + scg + 8];
    bf16x8 pv0 = *(const bf16x8*)&vtp[(size_t)srow * N_ + scg];
    bf16x8 pv1 = *(const bf16x8*)&vtp[(size_t)srow * N_ + scg + 8];

    for (int c = 0; c < 32; ++c) {
        __syncthreads();
        *(bf16x8*)&Kb[srow * KP + scg]     = pk0;
        *(bf16x8*)&Kb[srow * KP + scg + 8] = pk1;
        *(bf16x8*)&VT[srow * KP + scg]     = pv0;
        *(bf16x8*)&VT[srow * KP + scg + 8] = pv1;
        __syncthreads();
        if (c + 1 < 32) {
            const size_t kn = (size_t)((c + 1) * 64 + srow) * 64 + scg;
            const size_t vn = (size_t)srow * N_ + (c + 1) * 64 + scg;
            pk0 = *(const bf16x8*)&kbp[kn];
            pk1 = *(const bf16x8*)&kbp[kn + 8];
            pv0 = *(const bf16x8*)&vtp[vn];
            pv1 = *(const bf16x8*)&vtp[vn + 8];
        }

        // ---- S^T = K Q^T ----
        f32x4 s[4];
        #pragma unroll
        for (int t = 0; t < 4; ++t) {
            bf16x8 ka0 = *(const bf16x8*)&Kb[(t * 16 + m) * KP + quad * 8];
            bf16x8 ka1 = *(const bf16x8*)&Kb[(t * 16 + m) * KP + 32 + quad * 8];
            f32x4 z = {0.f, 0.f, 0.f, 0.f};
            z = __builtin_amdgcn_mfma_f32_16x16x32_bf16(ka0, qa0, z, 0, 0, 0);
            s[t] = __builtin_amdgcn_mfma_f32_16x16x32_bf16(ka1, qa1, z, 0, 0, 0);
        }

        // ---- p = exp2(s*scl); lsum; P -> strip (b64 writes) ----
        #pragma unroll
        for (int t = 0; t < 4; ++t) {
            float p0 = exp2f(s[t][0] * SCL), p1 = exp2f(s[t][1] * SCL);
            float p2 = exp2f(s[t][2] * SCL), p3 = exp2f(s[t][3] * SCL);
            lsum += p0 + p1 + p2 + p3;
            bf16x4 pk = {(__bf16)p0, (__bf16)p1, (__bf16)p2, (__bf16)p3};
            *(bf16x4*)&Pw[(prow + m) * KP + t * 16 + quad * 4] = pk;
        }
        asm volatile("s_waitcnt lgkmcnt(0)" ::: "memory");

        // ---- O += P V ----
        #pragma unroll
        for (int c2 = 0; c2 < 2; ++c2) {
            bf16x8 pa = *(const bf16x8*)&Pw[(prow + m) * KP + c2 * 32 + quad * 8];
            #pragma unroll
            for (int t = 0; t < 4; ++t) {
                bf16x8 vv = *(const bf16x8*)&VT[(t * 16 + m) * KP + c2 * 32 + quad * 8];
                O[t] = __builtin_amdgcn_mfma_f32_16x16x32_bf16(pa, vv, O[t], 0, 0, 0);
            }
        }
    }

    // lsum lives per (m, quad-partial) -> reduce across quads; qrow = prow+m
    lsum += __shfl_xor(lsum, 16, 64);
    lsum += __shfl_xor(lsum, 32, 64);
    if (lane < 16) lsl[prow + lane] = lsum;

    // stage mem^T, Gv^T into Kb/VT (tiles dead now)
    __syncthreads();
    for (int s2 = 0; s2 < 16; ++s2) {
        int flat = s2 * 256 + tid;          // flat = d*64 + e
        int d = flat >> 6, e = flat & 63;
        Kb[e * KP + d] = (__bf16)mem[(size_t)h * 4096 + flat];
        VT[e * KP + d] = (__bf16)Gv[(size_t)bh * 4096 + flat];
    }
    __syncthreads();

    // ---- gated path: num=eq@mem, mem_q=num/(eq*norm), o2=mem_q@Gv ----
    __bf16* op = o + ((size_t)bh * N_ + n0) * 64;
    bf16x8 ea0, ea1;
    #pragma unroll
    for (int j = 0; j < 8; ++j) {
        ea0[j] = (__bf16)eluf((float)qa0[j]);
        ea1[j] = (__bf16)eluf((float)qa1[j]);
    }
    f32x4 num[4];
    #pragma unroll
    for (int t = 0; t < 4; ++t) {
        bf16x8 b0 = *(const bf16x8*)&Kb[(t * 16 + m) * KP + quad * 8];
        bf16x8 b1 = *(const bf16x8*)&Kb[(t * 16 + m) * KP + 32 + quad * 8];
        f32x4 z = {0.f, 0.f, 0.f, 0.f};
        z = __builtin_amdgcn_mfma_f32_16x16x32_bf16(ea0, b0, z, 0, 0, 0);
        num[t] = __builtin_amdgcn_mfma_f32_16x16x32_bf16(ea1, b1, z, 0, 0, 0);
    }
    *(bf16x8*)&Pw[(prow + m) * KP + quad * 8]      = ea0;
    *(bf16x8*)&Pw[(prow + m) * KP + 32 + quad * 8] = ea1;
    asm volatile("s_waitcnt lgkmcnt(0)" ::: "memory");
    float mq[4][4];
    #pragma unroll
    for (int t = 0; t < 4; ++t)
        #pragma unroll
        for (int r = 0; r < 4; ++r) {
            float eqv = (float)Pw[(prow + quad * 4 + r) * KP + t * 16 + m];
            mq[t][r] = num[t][r] / (eqv * nrm_l[prow + quad * 4 + r]);
        }
    #pragma unroll
    for (int t = 0; t < 4; ++t)
        #pragma unroll
        for (int r = 0; r < 4; ++r)
            Pw[(prow + quad * 4 + r) * KP + t * 16 + m] = (__bf16)mq[t][r];
    asm volatile("s_waitcnt lgkmcnt(0)" ::: "memory");
    bf16x8 ma0 = *(const bf16x8*)&Pw[(prow + m) * KP + quad * 8];
    bf16x8 ma1 = *(const bf16x8*)&Pw[(prow + m) * KP + 32 + quad * 8];

    #pragma unroll
    for (int t = 0; t < 4; ++t) {
        bf16x8 g0 = *(const bf16x8*)&VT[(t * 16 + m) * KP + quad * 8];
        bf16x8 g1 = *(const bf16x8*)&VT[(t * 16 + m) * KP + 32 + quad * 8];
        f32x4 z = {0.f, 0.f, 0.f, 0.f};
        z = __builtin_amdgcn_mfma_f32_16x16x32_bf16(ma0, g0, z, 0, 0, 0);
        f32x4 o2 = __builtin_amdgcn_mfma_f32_16x16x32_bf16(ma1, g1, z, 0, 0, 0);
        #pragma unroll
        for (int r = 0; r < 4; ++r) {
            const int qr = prow + quad * 4 + r;
            float val = O[t][r] * (gl / lsl[qr]) + sigg * o2[r];
            op[(size_t)qr * 64 + t * 16 + m] = (__bf16)val;
        }
    }
}

// ---------------- K5: output projection on MFMA (unchanged) ----------------
__global__ __launch_bounds__(256) void k_outproj(
    const __bf16* __restrict__ o, const float* __restrict__ Wo,
    const float* __restrict__ bo, float* __restrict__ out)
{
    const int row0 = blockIdx.x * 64;      // over B*N
    const int b = row0 >> 11, nb = row0 & 2047;
    __shared__ __align__(16) __bf16 WoS[64 * 40];   // [dout][k] per 32-k block
    const int tid  = threadIdx.x;
    const int w    = tid >> 6, lane = tid & 63;
    const int quad = lane >> 4, m = lane & 15;

    f32x4 acc[4];
    #pragma unroll
    for (int t = 0; t < 4; ++t) { f32x4 z = {0.f, 0.f, 0.f, 0.f}; acc[t] = z; }

    for (int kbk = 0; kbk < 16; ++kbk) {
        for (int s2 = 0; s2 < 8; ++s2) {
            int flat = s2 * 256 + tid;      // flat = n*32 + kk
            int n = flat >> 5, kk = flat & 31;
            WoS[n * 40 + kk] = (__bf16)Wo[(size_t)n * 512 + kbk * 32 + kk];
        }
        __syncthreads();
        const int hc = kbk >> 1;
        size_t arow = (((size_t)b * H_ + hc) * N_ + nb + w * 16 + m);
        bf16x8 af = *(const bf16x8*)&o[arow * 64 + (kbk & 1) * 32 + quad * 8];
        #pragma unroll
        for (int t = 0; t < 4; ++t) {
            bf16x8 bf_ = *(const bf16x8*)&WoS[(t * 16 + m) * 40 + quad * 8];
            acc[t] = __builtin_amdgcn_mfma_f32_16x16x32_bf16(af, bf_, acc[t], 0, 0, 0);
        }
        __syncthreads();
    }
    #pragma unroll
    for (int t = 0; t < 4; ++t) {
        float bias = bo[t * 16 + m];
        #pragma unroll
        for (int r = 0; r < 4; ++r)
            out[(size_t)(row0 + w * 16 + quad * 4 + r) * 64 + t * 16 + m] =
                acc[t][r] + bias;
    }
}

extern "C" void kernel_launch(void* const* d_in, const int* in_sizes, int n_in,
                              void* d_out, int out_size, void* d_ws, size_t ws_size,
                              hipStream_t stream)
{
    const float* q        = (const float*)d_in[0];
    const float* k        = (const float*)d_in[1];
    const float* v        = (const float*)d_in[2];
    const float* Wq       = (const float*)d_in[3];
    const float* Wk       = (const float*)d_in[4];
    const float* Wv       = (const float*)d_in[5];
    const float* Wo       = (const float*)d_in[6];
    const float* bo       = (const float*)d_in[7];
    const float* Wg       = (const float*)d_in[8];
    const float* s_local  = (const float*)d_in[9];
    const float* s_long   = (const float*)d_in[10];
    const float* mem      = (const float*)d_in[11];
    const float* mem_norm = (const float*)d_in[12];

    float* ws = (float*)d_ws;
    float*  kh  = ws;
    __bf16* qb  = (__bf16*)(ws + 4194304);
    __bf16* kb  = (__bf16*)(ws + 6291456);
    __bf16* vb  = (__bf16*)(ws + 8388608);
    __bf16* vbT = (__bf16*)(ws + 10485760);
    float*  Gv  = ws + 12582912;
    float*  pm  = ws + 12713984;
    float*  pg  = ws + 14811136;
    __bf16* o   = (__bf16*)(ws + 12713984);   // aliases pm (dead after k_reduce)

    float* out      = (float*)d_out;
    float* out_mem  = out + 524288;
    float* out_norm = out + 655360;

    k_proj   <<<dim3(128, 8, 3), 256, 0, stream>>>(q, k, v, Wq, Wk, Wv,
                                                   qb, kh, kb, vb, vbT);
    k_memacc <<<dim3(16, 32),    256, 0, stream>>>(kh, vb, mem, mem_norm,
                                                   pm, out_norm);
    k_gv     <<<dim3(16, 32),    256, 0, stream>>>(Wg, vbT, pg);
    k_reduce <<<dim3(512),       256, 0, stream>>>(mem, pm, pg, out_mem, Gv);
    k_flash  <<<dim3(32, 32),    256, 0, stream>>>(qb, kb, vbT, mem, mem_norm, Gv,
                                                   s_local, s_long, o);
    k_outproj<<<dim3(128),       256, 0, stream>>>(o, Wo, bo, out);
}